// Round 6
// baseline (797.570 us; speedup 1.0000x reference)
//
#include <hip/hip_runtime.h>
#include <hip/hip_bf16.h>

#define BB   8
#define HH   64
#define WWID 64
#define CC   384
#define FF   1536
#define EE   8
#define LL   256
#define MTOTMAX 66560   // 65536 real rows + 8*128 max padding
#define NTMAX   520     // MTOTMAX/128

typedef unsigned short ushort_t;
typedef __attribute__((ext_vector_type(4))) unsigned short u16x4;
typedef __attribute__((ext_vector_type(8))) short          s16x8;  // 8 bf16 = 16B
typedef __attribute__((ext_vector_type(4))) float          f32x4;

__device__ __forceinline__ float bf2f(ushort_t u) {
  union { unsigned int i; float f; } v; v.i = ((unsigned int)u) << 16; return v.f;
}
__device__ __forceinline__ ushort_t f2bf(float f) {
  union { float f; unsigned int i; } v; v.f = f;
  unsigned int u = v.i;
  u += 0x7fffu + ((u >> 16) & 1u);
  return (ushort_t)(u >> 16);
}
// gelu exact via A&S 7.1.26 erf (|err|~1.5e-7 << bf16 rounding)
__device__ __forceinline__ float gelu_f(float x) {
  float u  = 0.70710678118654752f * x;
  float au = fabsf(u);
  float t  = 1.0f / (1.0f + 0.3275911f * au);
  float poly = t * (0.254829592f + t * (-0.284496736f + t * (1.421413741f +
               t * (-1.453152027f + t * 1.061405429f))));
  float ea = 1.0f - poly * __expf(-au * au);
  float erfv = (x < 0.f) ? -ea : ea;
  return 0.5f * x * (1.0f + erfv);
}

// async 16B/lane global->LDS; LDS dest = wave-uniform base + lane*16
#define GLDS(g, l) __builtin_amdgcn_global_load_lds( \
    (const __attribute__((address_space(1))) void*)(g), \
    (__attribute__((address_space(3))) void*)(l), 16, 0, 0)

// ---------------------------------------------------------------------------
// Transpose+cast: src f32 [E][R][Cd] -> dst bf16 [E][Cd][R]
// ---------------------------------------------------------------------------
__global__ __launch_bounds__(256) void k_transpose(const float* __restrict__ src,
                                                   ushort_t* __restrict__ dst,
                                                   int R, int Cd) {
  __shared__ ushort_t tile[32][33];
  int e  = blockIdx.z;
  int c0 = blockIdx.x * 32, r0 = blockIdx.y * 32;
  int tx = threadIdx.x & 31, ty = threadIdx.x >> 5;
  const float* s = src + (size_t)e * R * Cd;
  ushort_t*    d = dst + (size_t)e * R * Cd;
  #pragma unroll
  for (int i = 0; i < 32; i += 8)
    tile[ty + i][tx] = f2bf(s[(size_t)(r0 + ty + i) * Cd + c0 + tx]);
  __syncthreads();
  #pragma unroll
  for (int i = 0; i < 32; i += 8)
    d[(size_t)(c0 + ty + i) * R + r0 + tx] = tile[tx][ty + i];
}

// ---------------------------------------------------------------------------
// gw transpose: [E][C][16] f32 -> gwt [E][16][C] f32  (786 KB total)
// ---------------------------------------------------------------------------
__global__ void k_tgw(const float* __restrict__ gw, float* __restrict__ gwt) {
  int e = blockIdx.x, t = threadIdx.x;
  for (int i = t; i < CC * 16; i += 256) {
    int c = i >> 4, p = i & 15;
    gwt[((size_t)e * 16 + p) * CC + c] = gw[(size_t)e * CC * 16 + i];
  }
}

// ---------------------------------------------------------------------------
// Router: one block per (b, conv-patch l2); 8 expert-groups x 32 lanes,
// fully-coalesced f32x4 loads of x rows and gwt rows. fp32 -> softmax -> top2.
// ---------------------------------------------------------------------------
__global__ __launch_bounds__(256) void k_router(const float* __restrict__ x,
                                                const float* __restrict__ gwt,
                                                int* __restrict__ re, float* __restrict__ rw,
                                                int* __restrict__ cnt) {
  int bid = blockIdx.x;                 // b*256 + l2
  int b = bid >> 8, l2 = bid & 255;
  int hp = l2 >> 4, wp = l2 & 15;
  int t = threadIdx.x;
  int e = t >> 5, lane = t & 31;
  const float* xb = x + (size_t)b * (HH * WWID) * CC;
  const float* ge = gwt + (size_t)e * 16 * CC;
  float acc = 0.f;
  #pragma unroll
  for (int p = 0; p < 16; ++p) {
    int pix = (hp * 4 + (p >> 2)) * 64 + wp * 4 + (p & 3);
    const float* xr = xb + (size_t)pix * CC;
    const float* gr = ge + (size_t)p * CC;
    #pragma unroll
    for (int it = 0; it < 3; ++it) {
      f32x4 xv = *reinterpret_cast<const f32x4*>(xr + it * 128 + lane * 4);
      f32x4 gv = *reinterpret_cast<const f32x4*>(gr + it * 128 + lane * 4);
      acc += xv.x * gv.x + xv.y * gv.y + xv.z * gv.z + xv.w * gv.w;
    }
  }
  #pragma unroll
  for (int d = 16; d; d >>= 1) acc += __shfl_down(acc, d, 32);
  __shared__ float logits[EE];
  if (lane == 0) logits[e] = acc;
  __syncthreads();
  if (t == 0) {
    float m = logits[0];
    #pragma unroll
    for (int i = 1; i < EE; ++i) m = fmaxf(m, logits[i]);
    float p[EE]; float s = 0.f;
    #pragma unroll
    for (int i = 0; i < EE; ++i) { p[i] = __expf(logits[i] - m); s += p[i]; }
    #pragma unroll
    for (int i = 0; i < EE; ++i) p[i] /= s;
    int e0 = 0;
    #pragma unroll
    for (int i = 1; i < EE; ++i) if (p[i] > p[e0]) e0 = i;
    int e1 = (e0 == 0) ? 1 : 0;
    #pragma unroll
    for (int i = 0; i < EE; ++i) if (i != e0 && p[i] > p[e1]) e1 = i;
    float s2 = p[e0] + p[e1] + 1e-9f;
    re[bid * 2 + 0] = e0;  re[bid * 2 + 1] = e1;
    rw[bid * 2 + 0] = p[e0] / s2;  rw[bid * 2 + 1] = p[e1] / s2;
    atomicAdd(&cnt[e0], 16);
    atomicAdd(&cnt[e1], 16);
  }
}

// ---------------------------------------------------------------------------
// Pad/prefix (parallel): thread0 prefix in LDS; all threads fill tile2e + pad.
// ---------------------------------------------------------------------------
__global__ void k_pad(const int* __restrict__ cnt, int* __restrict__ cntp,
                      int* __restrict__ basep, int* __restrict__ tile2e,
                      int* __restrict__ gids, float* __restrict__ gwts) {
  __shared__ int s_cnt[EE], s_cntp[EE], s_base[EE + 1];
  int t = threadIdx.x;
  if (t == 0) {
    int b = 0;
    for (int e = 0; e < EE; ++e) {
      int c  = cnt[e];
      int cp = (c + 127) & ~127;
      s_cnt[e] = c; s_cntp[e] = cp; s_base[e] = b;
      b += cp;
    }
    s_base[EE] = b;
  }
  __syncthreads();
  if (t < EE) { cntp[t] = s_cntp[t]; basep[t] = s_base[t]; }
  if (t == EE) basep[EE] = s_base[EE];
  int ntot = s_base[EE] >> 7;
  for (int g = t; g < ntot; g += 256) {
    int e = 0;
    #pragma unroll
    for (int i = 1; i < EE; ++i) if (g * 128 >= s_base[i]) e = i;
    tile2e[g] = e;
  }
  for (int e = 0; e < EE; ++e)
    for (int i = s_cnt[e] + t; i < s_cntp[e]; i += 256) {
      gids[s_base[e] + i] = -1;
      gwts[s_base[e] + i] = 0.f;
    }
}

// ---------------------------------------------------------------------------
// Assign: one thread per (patch,slot); 16 pixel rows into compacted gids/gwts.
// id=(slot<<15)|pix; pix=b*4096+h*64+w; h=(l2&15)*4+((l2>>4)>>2),
// w=j*4+((l2>>4)&3)  (scramble from reference's U.reshape(B,C,L,k2)).
// ---------------------------------------------------------------------------
__global__ void k_assign(const int* __restrict__ re, const float* __restrict__ rw,
                         const int* __restrict__ basep, int* __restrict__ cnt2,
                         int* __restrict__ gids, float* __restrict__ gwts) {
  int i = blockIdx.x * blockDim.x + threadIdx.x;   // patch*2 + slot
  if (i >= BB * LL * 2) return;
  int pat = i >> 1, slot = i & 1;
  int b = pat >> 8, l2 = pat & 255;
  int e = re[i];
  float w = rw[i];
  int t2 = l2 >> 4, hp = l2 & 15;
  int kh = t2 >> 2, kw = t2 & 3;
  int h = hp * 4 + kh;
  int row = basep[e] + atomicAdd(&cnt2[e], 16);
  #pragma unroll
  for (int j = 0; j < 16; ++j) {
    int wpix = j * 4 + kw;
    int pix = (b << 12) + (h << 6) + wpix;
    gids[row + j] = (slot << 15) | pix;
    gwts[row + j] = w;
  }
}

// ---------------------------------------------------------------------------
// Gather chunk: x f32 rows -> Xc bf16 [local row][CC]; global tile = t0+bx.
// ---------------------------------------------------------------------------
__global__ __launch_bounds__(256) void k_gather(const float* __restrict__ x,
                                                const int* __restrict__ gids,
                                                const int* __restrict__ basep,
                                                ushort_t* __restrict__ Xc, int t0) {
  int g = t0 + blockIdx.x;
  if (g * 128 >= basep[EE]) return;
  __shared__ int s_id[128];
  int t = threadIdx.x;
  if (t < 128) s_id[t] = gids[g * 128 + t];
  __syncthreads();
  ushort_t* dst = Xc + (size_t)blockIdx.x * 128 * CC;
  for (int i = t; i < 128 * 96; i += 256) {
    int row = i / 96, ch = (i % 96) * 4;
    int id = s_id[row];
    f32x4 v = (f32x4){0.f, 0.f, 0.f, 0.f};
    if (id >= 0) v = *reinterpret_cast<const f32x4*>(x + (size_t)(id & 32767) * CC + ch);
    u16x4 o = {f2bf(v.x), f2bf(v.y), f2bf(v.z), f2bf(v.w)};
    *reinterpret_cast<u16x4*>(dst + (size_t)row * CC + ch) = o;
  }
}

// ---------------------------------------------------------------------------
// GEMM1 (A=W1 rows f, B=Xc rows m): Hc[m][f] = gelu(W1[f][c]·X[m][c] + b1[f]).
// 128(f) x 128(m) tile, BK=32.  D[row=f][col=m] -> each thread holds 4
// consecutive f for one m => dense u16x4 stores, NO LDS transpose.
// LDS: 8 chunks of 1KB per operand; chunk = 16rows x 32k frag-major
// (frag read = ds_read_b128 at chunk + lane*16, conflict-free).
// ---------------------------------------------------------------------------
__global__ __launch_bounds__(256, 4) void k_gemm1(const ushort_t* __restrict__ Xc,
                                                  const ushort_t* __restrict__ w1t,
                                                  const float* __restrict__ b1,
                                                  const int* __restrict__ basep,
                                                  const int* __restrict__ tile2e,
                                                  ushort_t* __restrict__ Hc, int t0) {
  int g = t0 + blockIdx.y;
  if (g * 128 >= basep[EE]) return;
  int e = tile2e[g], nb = blockIdx.x;
  __shared__ ushort_t As[4096];   // W1 slab rows f
  __shared__ ushort_t Bs[4096];   // Xc rows m
  int t = threadIdx.x, w = t >> 6, lane = t & 63;
  int l15 = lane & 15, q = lane >> 4;
  const ushort_t* a_src = w1t + ((size_t)e * FF + nb * 128) * CC;
  const ushort_t* b_src = Xc + (size_t)blockIdx.y * 128 * CC;
  int fh = (w & 1) * 4, mh = (w >> 1) * 4;   // chunk bases of 64x64 quadrant
  f32x4 acc[4][4];                            // [i=f][j=m]
  #pragma unroll
  for (int i = 0; i < 4; ++i)
    #pragma unroll
    for (int j = 0; j < 4; ++j) acc[i][j] = (f32x4){0.f, 0.f, 0.f, 0.f};

  for (int k0 = 0; k0 < CC; k0 += 32) {
    __syncthreads();
    #pragma unroll
    for (int c = 0; c < 2; ++c) {
      int ch = w * 2 + c;
      GLDS(a_src + (size_t)(ch * 16 + l15) * CC + k0 + q * 8, As + ch * 512);
      GLDS(b_src + (size_t)(ch * 16 + l15) * CC + k0 + q * 8, Bs + ch * 512);
    }
    __syncthreads();
    s16x8 af[4], bf[4];
    #pragma unroll
    for (int i = 0; i < 4; ++i)
      af[i] = *reinterpret_cast<const s16x8*>(As + (fh + i) * 512 + lane * 8);
    #pragma unroll
    for (int j = 0; j < 4; ++j)
      bf[j] = *reinterpret_cast<const s16x8*>(Bs + (mh + j) * 512 + lane * 8);
    #pragma unroll
    for (int i = 0; i < 4; ++i)
      #pragma unroll
      for (int j = 0; j < 4; ++j)
        acc[i][j] = __builtin_amdgcn_mfma_f32_16x16x32_bf16(af[i], bf[j], acc[i][j], 0, 0, 0);
  }

  // epilogue: +b1, gelu, dense 8-B stores Hc[m][f..f+3]
  ushort_t* hbase = Hc + (size_t)blockIdx.y * 128 * FF;
  int fb = nb * 128 + fh * 16 + q * 4;       // + i*16
  f32x4 bias[4];
  #pragma unroll
  for (int i = 0; i < 4; ++i)
    bias[i] = *reinterpret_cast<const f32x4*>(b1 + (size_t)e * FF + fb + i * 16);
  #pragma unroll
  for (int j = 0; j < 4; ++j) {
    int m = mh * 16 + j * 16 + l15;
    ushort_t* hp = hbase + (size_t)m * FF + fb;
    #pragma unroll
    for (int i = 0; i < 4; ++i) {
      u16x4 v;
      #pragma unroll
      for (int r = 0; r < 4; ++r)
        v[r] = f2bf(gelu_f(acc[i][j][r] + bias[i][r]));
      *reinterpret_cast<u16x4*>(hp + i * 16) = v;
    }
  }
}

// ---------------------------------------------------------------------------
// GEMM2 (A=W2t rows c, B=Hc rows m): y[id(m)][c] = (W2t[c][f]·H[m][f] + b2[c])*wt.
// Same structure, K=1536; dense u16x4 stores into scattered y rows.
// ---------------------------------------------------------------------------
__global__ __launch_bounds__(256, 4) void k_gemm2(const ushort_t* __restrict__ Hc,
                                                  const ushort_t* __restrict__ w2t,
                                                  const float* __restrict__ b2,
                                                  const int* __restrict__ basep,
                                                  const int* __restrict__ tile2e,
                                                  const int* __restrict__ gids,
                                                  const float* __restrict__ gwts,
                                                  ushort_t* __restrict__ y, int t0) {
  int g = t0 + blockIdx.y;
  if (g * 128 >= basep[EE]) return;
  int e = tile2e[g], nb = blockIdx.x;
  __shared__ ushort_t As[4096];
  __shared__ ushort_t Bs[4096];
  __shared__ int   s_id[128];
  __shared__ float s_w[128];
  int t = threadIdx.x, w = t >> 6, lane = t & 63;
  int l15 = lane & 15, q = lane >> 4;
  if (t < 128) {
    s_id[t] = gids[g * 128 + t];
    s_w[t]  = gwts[g * 128 + t];
  }
  const ushort_t* a_src = w2t + ((size_t)e * CC + nb * 128) * FF;
  const ushort_t* b_src = Hc + (size_t)blockIdx.y * 128 * FF;
  int chh = (w & 1) * 4, mh = (w >> 1) * 4;
  f32x4 acc[4][4];                            // [i=c][j=m]
  #pragma unroll
  for (int i = 0; i < 4; ++i)
    #pragma unroll
    for (int j = 0; j < 4; ++j) acc[i][j] = (f32x4){0.f, 0.f, 0.f, 0.f};

  for (int k0 = 0; k0 < FF; k0 += 32) {
    __syncthreads();
    #pragma unroll
    for (int c = 0; c < 2; ++c) {
      int ch = w * 2 + c;
      GLDS(a_src + (size_t)(ch * 16 + l15) * FF + k0 + q * 8, As + ch * 512);
      GLDS(b_src + (size_t)(ch * 16 + l15) * FF + k0 + q * 8, Bs + ch * 512);
    }
    __syncthreads();
    s16x8 af[4], bf[4];
    #pragma unroll
    for (int i = 0; i < 4; ++i)
      af[i] = *reinterpret_cast<const s16x8*>(As + (chh + i) * 512 + lane * 8);
    #pragma unroll
    for (int j = 0; j < 4; ++j)
      bf[j] = *reinterpret_cast<const s16x8*>(Bs + (mh + j) * 512 + lane * 8);
    #pragma unroll
    for (int i = 0; i < 4; ++i)
      #pragma unroll
      for (int j = 0; j < 4; ++j)
        acc[i][j] = __builtin_amdgcn_mfma_f32_16x16x32_bf16(af[i], bf[j], acc[i][j], 0, 0, 0);
  }

  // epilogue: +b2, *gate, dense 8-B stores y[id][c..c+3]
  int cb = nb * 128 + chh * 16 + q * 4;      // + i*16
  f32x4 bias[4];
  #pragma unroll
  for (int i = 0; i < 4; ++i)
    bias[i] = *reinterpret_cast<const f32x4*>(b2 + (size_t)e * CC + cb + i * 16);
  #pragma unroll
  for (int j = 0; j < 4; ++j) {
    int ml = mh * 16 + j * 16 + l15;
    int id = s_id[ml];
    if (id >= 0) {
      float wt = s_w[ml];
      ushort_t* yp = y + (size_t)id * CC + cb;
      #pragma unroll
      for (int i = 0; i < 4; ++i) {
        u16x4 v;
        #pragma unroll
        for (int r = 0; r < 4; ++r)
          v[r] = f2bf((acc[i][j][r] + bias[i][r]) * wt);
        *reinterpret_cast<u16x4*>(yp + i * 16) = v;
      }
    }
  }
}

// ---------------------------------------------------------------------------
// Finalize: out[b][h][c][w] = y[pix] + y[32768+pix]  (bf16 -> f32, transpose)
// ---------------------------------------------------------------------------
__global__ __launch_bounds__(256) void k_final(const ushort_t* __restrict__ y,
                                               float* __restrict__ out) {
  int bid = blockIdx.x;                 // b*64 + h
  __shared__ float tile[64][193];
  int t = threadIdx.x;
  float* dst = out + (size_t)bid * CC * WWID;   // [c][w]
  #pragma unroll
  for (int half = 0; half < 2; ++half) {
    int c0 = half * 192;
    for (int i = t; i < 64 * 48; i += 256) {
      int w = i / 48, c4 = (i % 48) * 4;
      int pix = (bid << 6) + w;
      u16x4 a = *reinterpret_cast<const u16x4*>(y + (size_t)pix * CC + c0 + c4);
      u16x4 b = *reinterpret_cast<const u16x4*>(y + (size_t)(32768 + pix) * CC + c0 + c4);
      #pragma unroll
      for (int k = 0; k < 4; ++k)
        tile[w][c4 + k] = bf2f(a[k]) + bf2f(b[k]);
    }
    __syncthreads();
    for (int i = t; i < 64 * 192; i += 256) {
      int cl = i / 64, w = i % 64;
      dst[(size_t)(c0 + cl) * WWID + w] = tile[w][cl];
    }
    __syncthreads();
  }
}

// ---------------------------------------------------------------------------
extern "C" void kernel_launch(void* const* d_in, const int* in_sizes, int n_in,
                              void* d_out, int out_size, void* d_ws, size_t ws_size,
                              hipStream_t stream) {
  const float* x  = (const float*)d_in[0];
  const float* gw = (const float*)d_in[1];
  const float* w1 = (const float*)d_in[2];
  const float* b1 = (const float*)d_in[3];
  const float* w2 = (const float*)d_in[4];
  const float* b2 = (const float*)d_in[5];

  const size_t fixed = (size_t)EE * FF * CC * 2 * 2   // w1t, w2t
                     + (size_t)65536 * CC * 2          // y
                     + (size_t)EE * 16 * CC * 4        // gwt
                     + (size_t)MTOTMAX * 4 * 2         // gids,gwts
                     + (size_t)BB * LL * 2 * 4 * 2     // re, rw
                     + (size_t)NTMAX * 4               // tile2e
                     + 1024;
  const int cands[10] = {66560, 57344, 49152, 40960, 32768, 16384, 8192, 4096, 2048, 1024};
  int MC = 1024;
  for (int i = 0; i < 10; ++i)
    if (fixed + (size_t)cands[i] * 3840 <= ws_size) { MC = cands[i]; break; }
  const int npass = (MTOTMAX + MC - 1) / MC;
  const int ntile = MC / 128;

  char* ws = (char*)d_ws;
  size_t off = 0;
  ushort_t* Xc   = (ushort_t*)(ws + off); off += (size_t)MC * CC * 2;
  ushort_t* Hc   = (ushort_t*)(ws + off); off += (size_t)MC * FF * 2;
  ushort_t* w1t  = (ushort_t*)(ws + off); off += (size_t)EE * FF * CC * 2;
  ushort_t* w2t  = (ushort_t*)(ws + off); off += (size_t)EE * FF * CC * 2;
  ushort_t* y    = (ushort_t*)(ws + off); off += (size_t)65536 * CC * 2;
  float* gwt   = (float*)(ws + off); off += (size_t)EE * 16 * CC * 4;
  int*   gids  = (int*)(ws + off);   off += (size_t)MTOTMAX * 4;
  float* gwts  = (float*)(ws + off); off += (size_t)MTOTMAX * 4;
  int*   re    = (int*)(ws + off);   off += (size_t)BB * LL * 2 * 4;
  float* rw    = (float*)(ws + off); off += (size_t)BB * LL * 2 * 4;
  int*   tile2e= (int*)(ws + off);   off += (size_t)NTMAX * 4;
  int*   cnt   = (int*)(ws + off);   off += 64;
  int*   cnt2  = (int*)(ws + off);   off += 64;
  int*   cntp  = (int*)(ws + off);   off += 64;
  int*   basep = (int*)(ws + off);   off += 64;

  hipMemsetAsync(cnt, 0, 128, stream);   // cnt + cnt2

  k_transpose<<<dim3(FF / 32, CC / 32, EE), 256, 0, stream>>>(w1, w1t, CC, FF); // [E][F][C]
  k_transpose<<<dim3(CC / 32, FF / 32, EE), 256, 0, stream>>>(w2, w2t, FF, CC); // [E][C][F]
  k_tgw<<<EE, 256, 0, stream>>>(gw, gwt);
  k_router<<<BB * LL, 256, 0, stream>>>(x, gwt, re, rw, cnt);
  k_pad<<<1, 256, 0, stream>>>(cnt, cntp, basep, tile2e, gids, gwts);
  k_assign<<<16, 256, 0, stream>>>(re, rw, basep, cnt2, gids, gwts);

  for (int p = 0; p < npass; ++p) {
    int t0 = p * ntile;
    k_gather<<<ntile, 256, 0, stream>>>(x, gids, basep, Xc, t0);
    k_gemm1<<<dim3(FF / 128, ntile), 256, 0, stream>>>(Xc, w1t, b1, basep, tile2e, Hc, t0);
    k_gemm2<<<dim3(CC / 128, ntile), 256, 0, stream>>>(Hc, w2t, b2, basep, tile2e, gids, gwts, y, t0);
  }
  k_final<<<BB * HH, 256, 0, stream>>>(y, (float*)d_out);
}

// Round 7
// 698.169 us; speedup vs baseline: 1.1424x; 1.1424x over previous
//
#include <hip/hip_runtime.h>
#include <hip/hip_bf16.h>

#define BB   8
#define HH   64
#define WWID 64
#define CC   384
#define FF   1536
#define EE   8
#define LL   256
#define MTOTMAX 66560   // 65536 real rows + 8*128 max padding
#define NTMAX   520     // MTOTMAX/128

typedef unsigned short ushort_t;
typedef __attribute__((ext_vector_type(4))) unsigned short u16x4;
typedef __attribute__((ext_vector_type(8))) short          s16x8;  // 8 bf16 = 16B
typedef __attribute__((ext_vector_type(4))) float          f32x4;

__device__ __forceinline__ float bf2f(ushort_t u) {
  union { unsigned int i; float f; } v; v.i = ((unsigned int)u) << 16; return v.f;
}
__device__ __forceinline__ ushort_t f2bf(float f) {
  union { float f; unsigned int i; } v; v.f = f;
  unsigned int u = v.i;
  u += 0x7fffu + ((u >> 16) & 1u);
  return (ushort_t)(u >> 16);
}
// gelu exact via A&S 7.1.26 erf (|err|~1.5e-7 << bf16 rounding)
__device__ __forceinline__ float gelu_f(float x) {
  float u  = 0.70710678118654752f * x;
  float au = fabsf(u);
  float t  = 1.0f / (1.0f + 0.3275911f * au);
  float poly = t * (0.254829592f + t * (-0.284496736f + t * (1.421413741f +
               t * (-1.453152027f + t * 1.061405429f))));
  float ea = 1.0f - poly * __expf(-au * au);
  float erfv = (x < 0.f) ? -ea : ea;
  return 0.5f * x * (1.0f + erfv);
}

// async 16B/lane global->LDS; LDS dest = wave-uniform base + lane*16
#define GLDS(g, l) __builtin_amdgcn_global_load_lds( \
    (const __attribute__((address_space(1))) void*)(g), \
    (__attribute__((address_space(3))) void*)(l), 16, 0, 0)

// ---------------------------------------------------------------------------
// Transpose+cast: src f32 [E][R][Cd] -> dst bf16 [E][Cd][R]
// ---------------------------------------------------------------------------
__global__ __launch_bounds__(256) void k_transpose(const float* __restrict__ src,
                                                   ushort_t* __restrict__ dst,
                                                   int R, int Cd) {
  __shared__ ushort_t tile[32][33];
  int e  = blockIdx.z;
  int c0 = blockIdx.x * 32, r0 = blockIdx.y * 32;
  int tx = threadIdx.x & 31, ty = threadIdx.x >> 5;
  const float* s = src + (size_t)e * R * Cd;
  ushort_t*    d = dst + (size_t)e * R * Cd;
  #pragma unroll
  for (int i = 0; i < 32; i += 8)
    tile[ty + i][tx] = f2bf(s[(size_t)(r0 + ty + i) * Cd + c0 + tx]);
  __syncthreads();
  #pragma unroll
  for (int i = 0; i < 32; i += 8)
    d[(size_t)(c0 + ty + i) * R + r0 + tx] = tile[tx][ty + i];
}

// ---------------------------------------------------------------------------
// gw transpose: [E][C][16] f32 -> gwt [E][16][C] f32
// ---------------------------------------------------------------------------
__global__ void k_tgw(const float* __restrict__ gw, float* __restrict__ gwt) {
  int e = blockIdx.x, t = threadIdx.x;
  for (int i = t; i < CC * 16; i += 256) {
    int c = i >> 4, p = i & 15;
    gwt[((size_t)e * 16 + p) * CC + c] = gw[(size_t)e * CC * 16 + i];
  }
}

// ---------------------------------------------------------------------------
// Router: one block per (b, conv-patch l2); coalesced f32x4; softmax -> top2.
// ---------------------------------------------------------------------------
__global__ __launch_bounds__(256) void k_router(const float* __restrict__ x,
                                                const float* __restrict__ gwt,
                                                int* __restrict__ re, float* __restrict__ rw,
                                                int* __restrict__ cnt) {
  int bid = blockIdx.x;                 // b*256 + l2
  int b = bid >> 8, l2 = bid & 255;
  int hp = l2 >> 4, wp = l2 & 15;
  int t = threadIdx.x;
  int e = t >> 5, lane = t & 31;
  const float* xb = x + (size_t)b * (HH * WWID) * CC;
  const float* ge = gwt + (size_t)e * 16 * CC;
  float acc = 0.f;
  #pragma unroll
  for (int p = 0; p < 16; ++p) {
    int pix = (hp * 4 + (p >> 2)) * 64 + wp * 4 + (p & 3);
    const float* xr = xb + (size_t)pix * CC;
    const float* gr = ge + (size_t)p * CC;
    #pragma unroll
    for (int it = 0; it < 3; ++it) {
      f32x4 xv = *reinterpret_cast<const f32x4*>(xr + it * 128 + lane * 4);
      f32x4 gv = *reinterpret_cast<const f32x4*>(gr + it * 128 + lane * 4);
      acc += xv.x * gv.x + xv.y * gv.y + xv.z * gv.z + xv.w * gv.w;
    }
  }
  #pragma unroll
  for (int d = 16; d; d >>= 1) acc += __shfl_down(acc, d, 32);
  __shared__ float logits[EE];
  if (lane == 0) logits[e] = acc;
  __syncthreads();
  if (t == 0) {
    float m = logits[0];
    #pragma unroll
    for (int i = 1; i < EE; ++i) m = fmaxf(m, logits[i]);
    float p[EE]; float s = 0.f;
    #pragma unroll
    for (int i = 0; i < EE; ++i) { p[i] = __expf(logits[i] - m); s += p[i]; }
    #pragma unroll
    for (int i = 0; i < EE; ++i) p[i] /= s;
    int e0 = 0;
    #pragma unroll
    for (int i = 1; i < EE; ++i) if (p[i] > p[e0]) e0 = i;
    int e1 = (e0 == 0) ? 1 : 0;
    #pragma unroll
    for (int i = 0; i < EE; ++i) if (i != e0 && p[i] > p[e1]) e1 = i;
    float s2 = p[e0] + p[e1] + 1e-9f;
    re[bid * 2 + 0] = e0;  re[bid * 2 + 1] = e1;
    rw[bid * 2 + 0] = p[e0] / s2;  rw[bid * 2 + 1] = p[e1] / s2;
    atomicAdd(&cnt[e0], 16);
    atomicAdd(&cnt[e1], 16);
  }
}

// ---------------------------------------------------------------------------
// Pad/prefix (parallel).
// ---------------------------------------------------------------------------
__global__ void k_pad(const int* __restrict__ cnt, int* __restrict__ cntp,
                      int* __restrict__ basep, int* __restrict__ tile2e,
                      int* __restrict__ gids, float* __restrict__ gwts) {
  __shared__ int s_cnt[EE], s_cntp[EE], s_base[EE + 1];
  int t = threadIdx.x;
  if (t == 0) {
    int b = 0;
    for (int e = 0; e < EE; ++e) {
      int c  = cnt[e];
      int cp = (c + 127) & ~127;
      s_cnt[e] = c; s_cntp[e] = cp; s_base[e] = b;
      b += cp;
    }
    s_base[EE] = b;
  }
  __syncthreads();
  if (t < EE) { cntp[t] = s_cntp[t]; basep[t] = s_base[t]; }
  if (t == EE) basep[EE] = s_base[EE];
  int ntot = s_base[EE] >> 7;
  for (int g = t; g < ntot; g += 256) {
    int e = 0;
    #pragma unroll
    for (int i = 1; i < EE; ++i) if (g * 128 >= s_base[i]) e = i;
    tile2e[g] = e;
  }
  for (int e = 0; e < EE; ++e)
    for (int i = s_cnt[e] + t; i < s_cntp[e]; i += 256) {
      gids[s_base[e] + i] = -1;
      gwts[s_base[e] + i] = 0.f;
    }
}

// ---------------------------------------------------------------------------
// Assign: one thread per (patch,slot); 16 pixel rows into compacted gids/gwts
// AND inverse map inv[slot*32768+pix] = global padded row.
// pix = b*4096 + h*64 + w; h=(l2&15)*4+((l2>>4)>>2), w=j*4+((l2>>4)&3).
// ---------------------------------------------------------------------------
__global__ void k_assign(const int* __restrict__ re, const float* __restrict__ rw,
                         const int* __restrict__ basep, int* __restrict__ cnt2,
                         int* __restrict__ gids, float* __restrict__ gwts,
                         int* __restrict__ inv) {
  int i = blockIdx.x * blockDim.x + threadIdx.x;   // patch*2 + slot
  if (i >= BB * LL * 2) return;
  int pat = i >> 1, slot = i & 1;
  int b = pat >> 8, l2 = pat & 255;
  int e = re[i];
  float w = rw[i];
  int t2 = l2 >> 4, hp = l2 & 15;
  int kh = t2 >> 2, kw = t2 & 3;
  int h = hp * 4 + kh;
  int row = basep[e] + atomicAdd(&cnt2[e], 16);
  #pragma unroll
  for (int j = 0; j < 16; ++j) {
    int wpix = j * 4 + kw;
    int pix = (b << 12) + (h << 6) + wpix;
    gids[row + j] = pix;
    gwts[row + j] = w;
    inv[(slot << 15) + pix] = row + j;
  }
}

// ---------------------------------------------------------------------------
// Gather chunk: x f32 rows -> Xc bf16 [local row][CC]; global tile = t0+bx.
// ---------------------------------------------------------------------------
__global__ __launch_bounds__(256) void k_gather(const float* __restrict__ x,
                                                const int* __restrict__ gids,
                                                const int* __restrict__ basep,
                                                ushort_t* __restrict__ Xc, int t0) {
  int g = t0 + blockIdx.x;
  if (g * 128 >= basep[EE]) return;
  __shared__ int s_id[128];
  int t = threadIdx.x;
  if (t < 128) s_id[t] = gids[g * 128 + t];
  __syncthreads();
  ushort_t* dst = Xc + (size_t)blockIdx.x * 128 * CC;
  for (int i = t; i < 128 * 96; i += 256) {
    int row = i / 96, ch = (i % 96) * 4;
    int id = s_id[row];
    f32x4 v = (f32x4){0.f, 0.f, 0.f, 0.f};
    if (id >= 0) v = *reinterpret_cast<const f32x4*>(x + (size_t)(id & 32767) * CC + ch);
    u16x4 o = {f2bf(v.x), f2bf(v.y), f2bf(v.z), f2bf(v.w)};
    *reinterpret_cast<u16x4*>(dst + (size_t)row * CC + ch) = o;
  }
}

// ---------------------------------------------------------------------------
// GEMM1: Hc[m][f] = gelu(W1[f][c] · Xc[m][c] + b1[f]).
// Block: 192 f x 128 m, K=384 (12 iters of BK=32).  256 thr / 4 waves,
// wave quadrant: (w&1)->f-half(96), (w>>1)->m-half(64): acc[6][4].
// LDS: A 12 chunks + B 8 chunks of 1KB (16rows x 32k, frag-major: reads are
// ds_read_b128 at chunk+lane*16, conflict-free).  Stage: 5 GLDS/wave/iter.
// Epilogue: dense u16x4 stores to Hc 128x192 slice (1.28x-amp proven).
// ---------------------------------------------------------------------------
__global__ __launch_bounds__(256, 3) void k_gemm1(const ushort_t* __restrict__ Xc,
                                                  const ushort_t* __restrict__ w1t,
                                                  const float* __restrict__ b1,
                                                  const int* __restrict__ basep,
                                                  const int* __restrict__ tile2e,
                                                  ushort_t* __restrict__ Hc, int t0) {
  int g = t0 + blockIdx.y;
  if (g * 128 >= basep[EE]) return;
  int e = tile2e[g], fg = blockIdx.x;    // f-group 0..7 (192 each)
  __shared__ ushort_t As[12 * 512];
  __shared__ ushort_t Bs[8 * 512];
  int t = threadIdx.x, w = t >> 6, lane = t & 63;
  int l15 = lane & 15, q = lane >> 4;
  const ushort_t* a_src = w1t + ((size_t)e * FF + fg * 192) * CC;
  const ushort_t* b_src = Xc + (size_t)blockIdx.y * 128 * CC;
  f32x4 acc[6][4];
  #pragma unroll
  for (int i = 0; i < 6; ++i)
    #pragma unroll
    for (int j = 0; j < 4; ++j) acc[i][j] = (f32x4){0.f, 0.f, 0.f, 0.f};

  for (int k0 = 0; k0 < CC; k0 += 32) {
    __syncthreads();
    #pragma unroll
    for (int c = 0; c < 5; ++c) {
      int ch = w * 5 + c;
      if (ch < 12) GLDS(a_src + (size_t)(ch * 16 + l15) * CC + k0 + q * 8, As + ch * 512);
      else         GLDS(b_src + (size_t)((ch - 12) * 16 + l15) * CC + k0 + q * 8, Bs + (ch - 12) * 512);
    }
    __syncthreads();
    s16x8 af[6], bf[4];
    #pragma unroll
    for (int i = 0; i < 6; ++i)
      af[i] = *reinterpret_cast<const s16x8*>(As + ((w & 1) * 6 + i) * 512 + lane * 8);
    #pragma unroll
    for (int j = 0; j < 4; ++j)
      bf[j] = *reinterpret_cast<const s16x8*>(Bs + ((w >> 1) * 4 + j) * 512 + lane * 8);
    #pragma unroll
    for (int i = 0; i < 6; ++i)
      #pragma unroll
      for (int j = 0; j < 4; ++j)
        acc[i][j] = __builtin_amdgcn_mfma_f32_16x16x32_bf16(af[i], bf[j], acc[i][j], 0, 0, 0);
  }

  // epilogue: +b1, gelu, dense u16x4 stores
  ushort_t* hbase = Hc + (size_t)blockIdx.y * 128 * FF;
  int fb = fg * 192 + (w & 1) * 96 + q * 4;   // + i*16
  f32x4 bias[6];
  #pragma unroll
  for (int i = 0; i < 6; ++i)
    bias[i] = *reinterpret_cast<const f32x4*>(b1 + (size_t)e * FF + fb + i * 16);
  #pragma unroll
  for (int j = 0; j < 4; ++j) {
    int m = (w >> 1) * 64 + j * 16 + l15;
    ushort_t* hp = hbase + (size_t)m * FF + fb;
    #pragma unroll
    for (int i = 0; i < 6; ++i) {
      u16x4 v;
      #pragma unroll
      for (int r = 0; r < 4; ++r)
        v[r] = f2bf(gelu_f(acc[i][j][r] + bias[i][r]));
      *reinterpret_cast<u16x4*>(hp + i * 16) = v;
    }
  }
}

// ---------------------------------------------------------------------------
// GEMM2: y_c[g*128+m][c] = (W2t[c][f] · Hc[m][f] + b2[c]) * wt[m]   (DENSE y)
// Block: 192 c x 128 m, K=1536 (48 iters).  Same template as gemm1.
// ---------------------------------------------------------------------------
__global__ __launch_bounds__(256, 3) void k_gemm2(const ushort_t* __restrict__ Hc,
                                                  const ushort_t* __restrict__ w2t,
                                                  const float* __restrict__ b2,
                                                  const int* __restrict__ basep,
                                                  const int* __restrict__ tile2e,
                                                  const float* __restrict__ gwts,
                                                  ushort_t* __restrict__ y, int t0) {
  int g = t0 + blockIdx.y;
  if (g * 128 >= basep[EE]) return;
  int e = tile2e[g], nb = blockIdx.x;    // c-group 0..1 (192 each)
  __shared__ ushort_t As[12 * 512];
  __shared__ ushort_t Bs[8 * 512];
  __shared__ float s_w[128];
  int t = threadIdx.x, w = t >> 6, lane = t & 63;
  int l15 = lane & 15, q = lane >> 4;
  if (t < 128) s_w[t] = gwts[g * 128 + t];
  const ushort_t* a_src = w2t + ((size_t)e * CC + nb * 192) * FF;
  const ushort_t* b_src = Hc + (size_t)blockIdx.y * 128 * FF;
  f32x4 acc[6][4];
  #pragma unroll
  for (int i = 0; i < 6; ++i)
    #pragma unroll
    for (int j = 0; j < 4; ++j) acc[i][j] = (f32x4){0.f, 0.f, 0.f, 0.f};

  for (int k0 = 0; k0 < FF; k0 += 32) {
    __syncthreads();
    #pragma unroll
    for (int c = 0; c < 5; ++c) {
      int ch = w * 5 + c;
      if (ch < 12) GLDS(a_src + (size_t)(ch * 16 + l15) * FF + k0 + q * 8, As + ch * 512);
      else         GLDS(b_src + (size_t)((ch - 12) * 16 + l15) * FF + k0 + q * 8, Bs + (ch - 12) * 512);
    }
    __syncthreads();
    s16x8 af[6], bf[4];
    #pragma unroll
    for (int i = 0; i < 6; ++i)
      af[i] = *reinterpret_cast<const s16x8*>(As + ((w & 1) * 6 + i) * 512 + lane * 8);
    #pragma unroll
    for (int j = 0; j < 4; ++j)
      bf[j] = *reinterpret_cast<const s16x8*>(Bs + ((w >> 1) * 4 + j) * 512 + lane * 8);
    #pragma unroll
    for (int i = 0; i < 6; ++i)
      #pragma unroll
      for (int j = 0; j < 4; ++j)
        acc[i][j] = __builtin_amdgcn_mfma_f32_16x16x32_bf16(af[i], bf[j], acc[i][j], 0, 0, 0);
  }

  // epilogue: +b2, *gate, dense u16x4 stores into compact y rows
  int cb = nb * 192 + (w & 1) * 96 + q * 4;   // + i*16
  f32x4 bias[6];
  #pragma unroll
  for (int i = 0; i < 6; ++i)
    bias[i] = *reinterpret_cast<const f32x4*>(b2 + (size_t)e * CC + cb + i * 16);
  ushort_t* ybase = y + (size_t)g * 128 * CC;
  #pragma unroll
  for (int j = 0; j < 4; ++j) {
    int m = (w >> 1) * 64 + j * 16 + l15;
    float wt = s_w[m];
    ushort_t* yp = ybase + (size_t)m * CC + cb;
    #pragma unroll
    for (int i = 0; i < 6; ++i) {
      u16x4 v;
      #pragma unroll
      for (int r = 0; r < 4; ++r)
        v[r] = f2bf((acc[i][j][r] + bias[i][r]) * wt);
      *reinterpret_cast<u16x4*>(yp + i * 16) = v;
    }
  }
}

// ---------------------------------------------------------------------------
// Finalize: out[b][h][c][w] = y_c[inv0[pix]][c] + y_c[inv1[pix]][c]
// ---------------------------------------------------------------------------
__global__ __launch_bounds__(256) void k_final(const ushort_t* __restrict__ y,
                                               const int* __restrict__ inv,
                                               float* __restrict__ out) {
  int bid = blockIdx.x;                 // b*64 + h
  __shared__ float tile[64][193];
  __shared__ int s_r0[64], s_r1[64];
  int t = threadIdx.x;
  if (t < 64) {
    s_r0[t] = inv[(bid << 6) + t];
    s_r1[t] = inv[32768 + (bid << 6) + t];
  }
  __syncthreads();
  float* dst = out + (size_t)bid * CC * WWID;   // [c][w]
  #pragma unroll
  for (int half = 0; half < 2; ++half) {
    int c0 = half * 192;
    for (int i = t; i < 64 * 48; i += 256) {
      int w = i / 48, c4 = (i % 48) * 4;
      u16x4 a = *reinterpret_cast<const u16x4*>(y + (size_t)s_r0[w] * CC + c0 + c4);
      u16x4 b = *reinterpret_cast<const u16x4*>(y + (size_t)s_r1[w] * CC + c0 + c4);
      #pragma unroll
      for (int k = 0; k < 4; ++k)
        tile[w][c4 + k] = bf2f(a[k]) + bf2f(b[k]);
    }
    __syncthreads();
    for (int i = t; i < 64 * 192; i += 256) {
      int cl = i / 64, w = i % 64;
      dst[(size_t)(c0 + cl) * WWID + w] = tile[w][cl];
    }
    __syncthreads();
  }
}

// ---------------------------------------------------------------------------
extern "C" void kernel_launch(void* const* d_in, const int* in_sizes, int n_in,
                              void* d_out, int out_size, void* d_ws, size_t ws_size,
                              hipStream_t stream) {
  const float* x  = (const float*)d_in[0];
  const float* gw = (const float*)d_in[1];
  const float* w1 = (const float*)d_in[2];
  const float* b1 = (const float*)d_in[3];
  const float* w2 = (const float*)d_in[4];
  const float* b2 = (const float*)d_in[5];

  const size_t fixed = (size_t)EE * FF * CC * 2 * 2   // w1t, w2t
                     + (size_t)MTOTMAX * CC * 2        // y (compact rows)
                     + (size_t)EE * 16 * CC * 4        // gwt
                     + (size_t)MTOTMAX * 4 * 2         // gids,gwts
                     + (size_t)65536 * 4               // inv
                     + (size_t)BB * LL * 2 * 4 * 2     // re, rw
                     + (size_t)NTMAX * 4               // tile2e
                     + 1024;
  const int cands[6] = {32768, 16384, 8192, 4096, 2048, 1024};   // cap 32768: smaller Hc chunk = better L3 residency
  int MC = 1024;
  for (int i = 0; i < 6; ++i)
    if (fixed + (size_t)cands[i] * 3840 <= ws_size) { MC = cands[i]; break; }
  const int npass = (MTOTMAX + MC - 1) / MC;
  const int ntile = MC / 128;

  char* ws = (char*)d_ws;
  size_t off = 0;
  ushort_t* Xc   = (ushort_t*)(ws + off); off += (size_t)MC * CC * 2;
  ushort_t* Hc   = (ushort_t*)(ws + off); off += (size_t)MC * FF * 2;
  ushort_t* w1t  = (ushort_t*)(ws + off); off += (size_t)EE * FF * CC * 2;
  ushort_t* w2t  = (ushort_t*)(ws + off); off += (size_t)EE * FF * CC * 2;
  ushort_t* y    = (ushort_t*)(ws + off); off += (size_t)MTOTMAX * CC * 2;
  float* gwt   = (float*)(ws + off); off += (size_t)EE * 16 * CC * 4;
  int*   gids  = (int*)(ws + off);   off += (size_t)MTOTMAX * 4;
  float* gwts  = (float*)(ws + off); off += (size_t)MTOTMAX * 4;
  int*   inv   = (int*)(ws + off);   off += (size_t)65536 * 4;
  int*   re    = (int*)(ws + off);   off += (size_t)BB * LL * 2 * 4;
  float* rw    = (float*)(ws + off); off += (size_t)BB * LL * 2 * 4;
  int*   tile2e= (int*)(ws + off);   off += (size_t)NTMAX * 4;
  int*   cnt   = (int*)(ws + off);   off += 64;
  int*   cnt2  = (int*)(ws + off);   off += 64;
  int*   cntp  = (int*)(ws + off);   off += 64;
  int*   basep = (int*)(ws + off);   off += 64;

  hipMemsetAsync(cnt, 0, 128, stream);   // cnt + cnt2

  k_transpose<<<dim3(FF / 32, CC / 32, EE), 256, 0, stream>>>(w1, w1t, CC, FF); // [E][F][C]
  k_transpose<<<dim3(CC / 32, FF / 32, EE), 256, 0, stream>>>(w2, w2t, FF, CC); // [E][C][F]
  k_tgw<<<EE, 256, 0, stream>>>(gw, gwt);
  k_router<<<BB * LL, 256, 0, stream>>>(x, gwt, re, rw, cnt);
  k_pad<<<1, 256, 0, stream>>>(cnt, cntp, basep, tile2e, gids, gwts);
  k_assign<<<16, 256, 0, stream>>>(re, rw, basep, cnt2, gids, gwts, inv);

  for (int p = 0; p < npass; ++p) {
    int t0 = p * ntile;
    k_gather<<<ntile, 256, 0, stream>>>(x, gids, basep, Xc, t0);
    k_gemm1<<<dim3(FF / 192, ntile), 256, 0, stream>>>(Xc, w1t, b1, basep, tile2e, Hc, t0);
    k_gemm2<<<dim3(CC / 192, ntile), 256, 0, stream>>>(Hc, w2t, b2, basep, tile2e, gwts, y, t0);
  }
  k_final<<<BB * HH, 256, 0, stream>>>(y, inv, (float*)d_out);
}